// Round 21
// baseline (338.301 us; speedup 1.0000x reference)
//
#include <hip/hip_runtime.h>
#include <hip/hip_bf16.h>
#include <math.h>

#define NNODES 50000
#define NEDGE 625000
#define RREL 16
#define SCAN_NB 196   // ceil(50000/256)

typedef __attribute__((ext_vector_type(8))) short short8;
typedef __attribute__((ext_vector_type(4))) float f32x4;

__device__ __forceinline__ float bfu(ushort u) {
  return __uint_as_float(((unsigned)u) << 16);
}
__device__ __forceinline__ ushort f2b(float f) {
  __hip_bfloat16 h = __float2bfloat16(f);
  return *(ushort*)&h;
}

// ---------------- mega_prep: weight prep + bias1 fold-prep + edge counts ----------
__global__ __launch_bounds__(256) void mega_prep(
    const float* __restrict__ ipw, const float* __restrict__ opw,
    const float* __restrict__ w1, const float* __restrict__ root1,
    const float* __restrict__ w2, const float* __restrict__ root2,
    const float* __restrict__ opb,
    const int* __restrict__ dst, const int* __restrict__ et,
    __hip_bfloat16* __restrict__ BTqkv, __hip_bfloat16* __restrict__ BToutT,
    __hip_bfloat16* __restrict__ BT1, __hip_bfloat16* __restrict__ BT2,
    float* __restrict__ bias1, int* __restrict__ cnt) {
  int b = blockIdx.x, t = threadIdx.x;
  if (b < 944) {
    int i = b * 256 + t;
    if (i < 49152) {
      BTqkv[i] = __float2bfloat16(ipw[i]);
    } else if (i < 65536) {
      int j = i - 49152; int m = j / 128, c = j % 128;
      BToutT[j] = __float2bfloat16(opw[c * 128 + m]);
    } else if (i < 65536 + 139264) {
      int j = i - 65536; int c = j / 128, k = j % 128;
      float v;
      if (c < 64) v = root1[k * 64 + c];
      else { int r = (c - 64) >> 6, o = (c - 64) & 63; v = w1[r * 8192 + k * 64 + o]; }
      BT1[j] = __float2bfloat16(v);
    } else if (i < 65536 + 139264 + 34816) {
      int j = i - 65536 - 139264; int c = j / 64, k = j % 64;
      float v;
      if (c < 32) v = root2[k * 32 + c];
      else { int r = (c - 32) >> 5, o = (c - 32) & 31; v = w2[r * 2048 + k * 32 + o]; }
      BT2[j] = __float2bfloat16(v);
    }
  } else if (b < 949) {
    int j = (b - 944) * 256 + t;
    if (j < 1088) {
      float s = 0.f;
      if (j < 64) {
        for (int c = 0; c < 128; c++) s += opb[c] * root1[c * 64 + j];
      } else {
        int r = (j - 64) >> 6, o = (j - 64) & 63;
        for (int c = 0; c < 128; c++) s += opb[c] * w1[r * 8192 + c * 64 + o];
      }
      bias1[j] = s;
    }
  } else {
    int e = (b - 949) * 256 + t;
    if (e < NEDGE) atomicAdd(&cnt[et[e] * NNODES + dst[e]], 1);
  }
}

// ---------------- shared QKV strip body (batched f32 A staging, one strip) --------
__device__ __forceinline__ void qkv_strip_body(
    const float* __restrict__ A, const ushort* __restrict__ BT,
    const float* __restrict__ bias, ushort* __restrict__ C,
    long row0, int col0, long Meff, ushort* As, ushort* Cs) {
  const int t = threadIdx.x;

  // batched staging: issue ALL 16 loads, then cvt+LDS
  {
    float4 fa[16];
#pragma unroll
    for (int it = 0; it < 8; it++) {
      int c = t + it * 256;
      int r = c >> 4, cc = c & 15;
      long gm = row0 + r; if (gm > 199999) gm = 199999;
      const float* ap = A + gm * 128 + cc * 8;
      fa[2 * it]     = *(const float4*)ap;
      fa[2 * it + 1] = *(const float4*)(ap + 4);
    }
#pragma unroll
    for (int it = 0; it < 8; it++) {
      int c = t + it * 256;
      int r = c >> 4, cc = c & 15;
      int4 v = make_int4(0, 0, 0, 0);
      if (row0 + r < 200000) {
        float4 f0 = fa[2 * it], f1 = fa[2 * it + 1];
        v.x = (int)f2b(f0.x) | ((int)f2b(f0.y) << 16);
        v.y = (int)f2b(f0.z) | ((int)f2b(f0.w) << 16);
        v.z = (int)f2b(f1.x) | ((int)f2b(f1.y) << 16);
        v.w = (int)f2b(f1.z) | ((int)f2b(f1.w) << 16);
      }
      *(int4*)(As + r * 128 + ((cc ^ (r & 7)) * 8)) = v;
    }
  }
  __syncthreads();

  const int lane = t & 63, w = t >> 6;
  const int wr = (w >> 1) * 64, wc = (w & 1) * 64;
  const int lrow = lane & 15, lk = lane >> 4;

  const ushort* bp[4];
#pragma unroll
  for (int j = 0; j < 4; j++)
    bp[j] = BT + (long)(col0 + wc + j * 16 + lrow) * 128 + lk * 8;

  short8 bfr[4][4];
#pragma unroll
  for (int k0 = 0; k0 < 4; k0++)
#pragma unroll
    for (int j = 0; j < 4; j++)
      bfr[k0][j] = *(const short8*)(bp[j] + k0 * 32);

  f32x4 acc[4][4];
#pragma unroll
  for (int i = 0; i < 4; i++)
#pragma unroll
    for (int j = 0; j < 4; j++) acc[i][j] = (f32x4){0.f, 0.f, 0.f, 0.f};

#pragma unroll
  for (int k0 = 0; k0 < 4; k0++) {
    const int cb = k0 * 4 + lk;
    short8 af[4];
#pragma unroll
    for (int i = 0; i < 4; i++) {
      int ra = wr + i * 16 + lrow;
      af[i] = *(const short8*)(As + ra * 128 + ((cb ^ (ra & 7)) * 8));
    }
#pragma unroll
    for (int i = 0; i < 4; i++)
#pragma unroll
      for (int j = 0; j < 4; j++)
        acc[i][j] = __builtin_amdgcn_mfma_f32_16x16x32_bf16(af[i], bfr[k0][j], acc[i][j], 0, 0, 0);
  }

  // epilogue: bf16 C-tile in LDS, coalesced int4 stores
#pragma unroll
  for (int j = 0; j < 4; j++) {
    int coll = wc + j * 16 + lrow;
    float bv = bias[col0 + coll];
#pragma unroll
    for (int i = 0; i < 4; i++) {
      int rbase = wr + i * 16 + lk * 4;
#pragma unroll
      for (int q = 0; q < 4; q++)
        Cs[(rbase + q) * 136 + coll] = f2b(acc[i][j][q] + bv);
    }
  }
  __syncthreads();
#pragma unroll
  for (int idx = t; idx < 128 * 16; idx += 256) {
    int r = idx >> 4, k = idx & 15;
    long gm = row0 + r;
    if (gm < Meff)
      *(int4*)(C + gm * 384 + col0 + k * 8) = *(const int4*)(Cs + r * 136 + k * 8);
  }
}

// K/V strips: grid (2, 1563) — x = strip (L2-reuse of A between the pair), y = row
__global__ __launch_bounds__(256) void qkv_kv(
    const float* __restrict__ A, const __hip_bfloat16* __restrict__ BT,
    const float* __restrict__ bias, __hip_bfloat16* __restrict__ C) {
  __shared__ ushort As[128 * 128];
  __shared__ ushort Cs[128 * 136];
  qkv_strip_body(A, (const ushort*)BT, bias, (ushort*)C,
                 (long)blockIdx.y * 128, 128 + (int)blockIdx.x * 128, 200000, As, Cs);
}

// Q strip: rows < 50000 only (A L3-hot by launch time)
__global__ __launch_bounds__(256) void qkv_q(
    const float* __restrict__ A, const __hip_bfloat16* __restrict__ BT,
    const float* __restrict__ bias, __hip_bfloat16* __restrict__ C) {
  __shared__ ushort As[128 * 128];
  __shared__ ushort Cs[128 * 136];
  qkv_strip_body(A, (const ushort*)BT, bias, (ushort*)C,
                 (long)blockIdx.x * 128, 0, NNODES, As, Cs);
}

// ---------------- generic strip-loop bf16 GEMM (batched A + hoisted B) ------------
#define EPILOGUE_STORE(MEFF, NCOLS, LDC, BIASEXPR)                              \
  for (int p = 0; p < 2; p++) {                                                 \
    __syncthreads();                                                            \
    if ((w >> 1) == p) {                                                        \
      _Pragma("unroll")                                                         \
      for (int j = 0; j < 4; j++) {                                             \
        int coll = wc + j * 16 + lrow;                                          \
        float bv = (BIASEXPR);                                                  \
        _Pragma("unroll")                                                       \
        for (int i = 0; i < 4; i++) {                                           \
          int rloc = i * 16 + lk * 4;                                           \
          _Pragma("unroll")                                                     \
          for (int q = 0; q < 4; q++)                                           \
            Cs[(rloc + q) * 132 + coll] = f2b(acc[i][j][q] + bv);               \
        }                                                                       \
      }                                                                         \
    }                                                                           \
    __syncthreads();                                                            \
    _Pragma("unroll")                                                           \
    for (int idx = t; idx < 64 * 16; idx += 256) {                              \
      int r = idx >> 4, k = idx & 15;                                           \
      long gm = row0 + p * 64 + r;                                              \
      int col = col0 + k * 8;                                                   \
      if (gm < (MEFF) && col < (NCOLS))                                         \
        *(int4*)((ushort*)C + gm * (LDC) + col) = *(const int4*)(Cs + r * 132 + k * 8); \
    }                                                                           \
  }

template <int K>
__global__ __launch_bounds__(256) void gemm_strips(
    const __hip_bfloat16* __restrict__ Av, const __hip_bfloat16* __restrict__ BT,
    const float* __restrict__ bias, __hip_bfloat16* __restrict__ C,
    int M, int N, int ldc, int spg) {
  constexpr int CPR = K / 8;
  constexpr int NIT = 128 * CPR / 256;
  constexpr int NK0 = K / 32;
  __shared__ ushort As[128 * K];
  __shared__ ushort Cs[64 * 132];
  const int t = threadIdx.x;
  const long row0 = (long)blockIdx.x * 128;

  {
    int4 st[NIT];
#pragma unroll
    for (int it = 0; it < NIT; it++) {
      int c = t + it * 256;
      int r = c / CPR, cc = c % CPR;
      long gm = row0 + r; if (gm > M - 1) gm = M - 1;
      st[it] = *(const int4*)((const ushort*)Av + gm * K + cc * 8);
    }
#pragma unroll
    for (int it = 0; it < NIT; it++) {
      int c = t + it * 256;
      int r = c / CPR, cc = c % CPR;
      int4 v = (row0 + r < M) ? st[it] : make_int4(0, 0, 0, 0);
      *(int4*)(As + r * K + ((cc ^ (r & 7)) * 8)) = v;
    }
  }
  __syncthreads();

  const int lane = t & 63, w = t >> 6;
  const int wr = (w >> 1) * 64, wc = (w & 1) * 64;
  const int lrow = lane & 15, lk = lane >> 4;
  const int nstrips = (N + 127) / 128;
  const int sbeg = blockIdx.y * spg;
  const int send = min(sbeg + spg, nstrips);

  for (int s = sbeg; s < send; s++) {
    const int col0 = s * 128;

    const ushort* bp[4];
#pragma unroll
    for (int j = 0; j < 4; j++) {
      int gn = col0 + wc + j * 16 + lrow;
      if (gn > N - 1) gn = N - 1;
      bp[j] = (const ushort*)BT + (long)gn * K + lk * 8;
    }

    short8 bfr[NK0][4];
#pragma unroll
    for (int k0 = 0; k0 < NK0; k0++)
#pragma unroll
      for (int j = 0; j < 4; j++)
        bfr[k0][j] = *(const short8*)(bp[j] + k0 * 32);

    f32x4 acc[4][4];
#pragma unroll
    for (int i = 0; i < 4; i++)
#pragma unroll
      for (int j = 0; j < 4; j++) acc[i][j] = (f32x4){0.f, 0.f, 0.f, 0.f};

#pragma unroll
    for (int k0 = 0; k0 < NK0; k0++) {
      const int cb = k0 * 4 + lk;
      short8 af[4];
#pragma unroll
      for (int i = 0; i < 4; i++) {
        int ra = wr + i * 16 + lrow;
        af[i] = *(const short8*)(As + ra * K + ((cb ^ (ra & 7)) * 8));
      }
#pragma unroll
      for (int i = 0; i < 4; i++)
#pragma unroll
        for (int j = 0; j < 4; j++)
          acc[i][j] = __builtin_amdgcn_mfma_f32_16x16x32_bf16(af[i], bfr[k0][j], acc[i][j], 0, 0, 0);
    }

    EPILOGUE_STORE(M, N, ldc, bias ? bias[min(col0 + coll, N - 1)] : 0.f)
  }
}

// ---------------- attention: 4 nodes/wave, int4 loads -----------------------------
__global__ __launch_bounds__(256) void attn_kernel(
    const __hip_bfloat16* __restrict__ qkv, __hip_bfloat16* __restrict__ o0) {
  int w = threadIdx.x >> 6, lane = threadIdx.x & 63;
  int nl = lane >> 4, cl = lane & 15;
  long n = (long)blockIdx.x * 16 + w * 4 + nl;
  const ushort* base = (const ushort*)qkv;
  int4 qv = *(const int4*)(base + n * 384 + cl * 8);
  int4 kq[4], vq[4];
#pragma unroll
  for (int m = 0; m < 4; m++) {
    const ushort* p = base + ((long)m * NNODES + n) * 384;
    kq[m] = *(const int4*)(p + 128 + cl * 8);
    vq[m] = *(const int4*)(p + 256 + cl * 8);
  }
  float qf[8];
  {
    const uint* qu = (const uint*)&qv;
#pragma unroll
    for (int x = 0; x < 4; x++) {
      qf[2 * x] = bfu(qu[x] & 0xffff);
      qf[2 * x + 1] = bfu(qu[x] >> 16);
    }
  }
  float s[4];
#pragma unroll
  for (int m = 0; m < 4; m++) {
    const uint* ku = (const uint*)&kq[m];
    float p = 0.f;
#pragma unroll
    for (int x = 0; x < 4; x++)
      p += qf[2 * x] * bfu(ku[x] & 0xffff) + qf[2 * x + 1] * bfu(ku[x] >> 16);
    p += __shfl_xor(p, 1);
    p += __shfl_xor(p, 2);
    s[m] = p * 0.17677669529663687f;  // 1/sqrt(32)
  }
  float mx = fmaxf(fmaxf(s[0], s[1]), fmaxf(s[2], s[3]));
  float e[4], sum = 0.f;
#pragma unroll
  for (int m = 0; m < 4; m++) { e[m] = __expf(s[m] - mx); sum += e[m]; }
  float inv = 1.0f / sum;
  float o[8] = {0.f, 0.f, 0.f, 0.f, 0.f, 0.f, 0.f, 0.f};
#pragma unroll
  for (int m = 0; m < 4; m++) {
    const uint* vu = (const uint*)&vq[m];
    float wgt = e[m] * inv;
#pragma unroll
    for (int x = 0; x < 4; x++) {
      o[2 * x]     += wgt * bfu(vu[x] & 0xffff);
      o[2 * x + 1] += wgt * bfu(vu[x] >> 16);
    }
  }
  int4 ov;
  uint* ou = (uint*)&ov;
#pragma unroll
  for (int x = 0; x < 4; x++)
    ou[x] = (uint)f2b(o[2 * x]) | ((uint)f2b(o[2 * x + 1]) << 16);
  *(int4*)((ushort*)o0 + n * 128 + cl * 8) = ov;
}

// ---------------- CSR build ------------------------------------------------------
__global__ __launch_bounds__(256) void scan1(
    const int* __restrict__ cnt, int* __restrict__ off, int* __restrict__ part) {
  int t = threadIdx.x, b = blockIdx.x;
  int i = b * 256 + t;
  int v = 0;
  if (i < NNODES) {
#pragma unroll
    for (int r = 0; r < RREL; r++) v += cnt[r * NNODES + i];
  }
  __shared__ int sm[256];
  sm[t] = v;
  __syncthreads();
#pragma unroll
  for (int o = 1; o < 256; o <<= 1) {
    int x = (t >= o) ? sm[t - o] : 0;
    __syncthreads();
    sm[t] += x;
    __syncthreads();
  }
  if (i < NNODES) off[i] = sm[t] - v;
  if (t == 255) part[b] = sm[t];
}

__global__ __launch_bounds__(256) void scan2(int* __restrict__ part) {
  int t = threadIdx.x;
  int v = (t < SCAN_NB) ? part[t] : 0;
  __shared__ int sm[256];
  sm[t] = v;
  __syncthreads();
#pragma unroll
  for (int o = 1; o < 256; o <<= 1) {
    int x = (t >= o) ? sm[t - o] : 0;
    __syncthreads();
    sm[t] += x;
    __syncthreads();
  }
  if (t < SCAN_NB) part[t] = sm[t] - v;
}

__global__ __launch_bounds__(256) void scan3(int* __restrict__ off, const int* __restrict__ part) {
  int i = blockIdx.x * 256 + threadIdx.x;
  if (i < NNODES) off[i] += part[blockIdx.x];
  if (i == 0) off[NNODES] = NEDGE;
}

__global__ __launch_bounds__(256) void scatter_edges(
    const int* __restrict__ src, const int* __restrict__ dst, const int* __restrict__ et,
    const int* __restrict__ cnt, const int* __restrict__ off,
    int* __restrict__ fill, unsigned* __restrict__ sorted, float* __restrict__ scales) {
  int e = blockIdx.x * 256 + threadIdx.x;
  if (e >= NEDGE) return;
  int d = dst[e], r = et[e], s = src[e];
  int pos = off[d] + atomicAdd(&fill[d], 1);
  sorted[pos] = (unsigned)s | ((unsigned)r << 16);
  scales[pos] = 1.0f / (float)cnt[r * NNODES + d];
}

// ---------------- fused layer1: 8-deep gather pipeline + relu ---------------------
__global__ __launch_bounds__(256) void fused1(
    const int* __restrict__ off, const unsigned* __restrict__ sorted,
    const float* __restrict__ scales, const ushort* __restrict__ Y1,
    const float* __restrict__ b1, __hip_bfloat16* __restrict__ x1b) {
  int w = threadIdx.x >> 6, lane = threadIdx.x & 63;
  int d = blockIdx.x * 4 + w;
  int s0 = off[d], s1 = off[d + 1];
  float a[8];
  a[0] = bfu(Y1[(size_t)d * 1088 + lane]) + b1[lane];
#pragma unroll
  for (int j = 1; j < 8; j++) a[j] = 0.f;
  int i = s0;
  for (; i + 7 < s1; i += 8) {
    unsigned p[8];
    float c[8];
#pragma unroll
    for (int j = 0; j < 8; j++) { p[j] = sorted[i + j]; c[j] = scales[i + j]; }
#pragma unroll
    for (int j = 0; j < 8; j++)
      a[j] += bfu(Y1[(size_t)(p[j] & 0xFFFF) * 1088 + 64 + (p[j] >> 16) * 64 + lane]) * c[j];
  }
  for (; i < s1; i++) {
    unsigned p = sorted[i];
    a[0] += bfu(Y1[(size_t)(p & 0xFFFF) * 1088 + 64 + (p >> 16) * 64 + lane]) * scales[i];
  }
  float acc = ((a[0] + a[1]) + (a[2] + a[3])) + ((a[4] + a[5]) + (a[6] + a[7]));
  x1b[(size_t)d * 64 + lane] = __float2bfloat16(fmaxf(acc, 0.f));
}

// ---------------- fused layer2: 4-way (2 lanes x 2 accs) + softmax -> out ---------
__global__ __launch_bounds__(256) void fused2(
    const int* __restrict__ off, const unsigned* __restrict__ sorted,
    const float* __restrict__ scales, const ushort* __restrict__ Y2,
    const float* __restrict__ b2, float* __restrict__ out) {
  int w = threadIdx.x >> 6, lane = threadIdx.x & 63;
  int d = blockIdx.x * 4 + w;
  int j = lane & 31, half = lane >> 5;
  int s0 = off[d], s1 = off[d + 1];
  float a0 = 0.f, a1 = 0.f, a2 = 0.f, a3 = 0.f;
  int i = s0 + half;
  for (; i + 6 < s1; i += 8) {
    unsigned p0 = sorted[i], p1 = sorted[i + 2], p2 = sorted[i + 4], p3 = sorted[i + 6];
    float c0 = scales[i], c1 = scales[i + 2], c2 = scales[i + 4], c3 = scales[i + 6];
    a0 += bfu(Y2[(size_t)(p0 & 0xFFFF) * 544 + 32 + (p0 >> 16) * 32 + j]) * c0;
    a1 += bfu(Y2[(size_t)(p1 & 0xFFFF) * 544 + 32 + (p1 >> 16) * 32 + j]) * c1;
    a2 += bfu(Y2[(size_t)(p2 & 0xFFFF) * 544 + 32 + (p2 >> 16) * 32 + j]) * c2;
    a3 += bfu(Y2[(size_t)(p3 & 0xFFFF) * 544 + 32 + (p3 >> 16) * 32 + j]) * c3;
  }
  for (; i < s1; i += 2) {
    unsigned p = sorted[i];
    a0 += bfu(Y2[(size_t)(p & 0xFFFF) * 544 + 32 + (p >> 16) * 32 + j]) * scales[i];
  }
  float acc = (a0 + a1) + (a2 + a3);
  acc += __shfl_xor(acc, 32);
  float v = acc + bfu(Y2[(size_t)d * 544 + j]) + b2[j];
  float mx = v;
#pragma unroll
  for (int o = 16; o; o >>= 1) mx = fmaxf(mx, __shfl_xor(mx, o));
  float e = __expf(v - mx);
  float sum = e;
#pragma unroll
  for (int o = 16; o; o >>= 1) sum += __shfl_xor(sum, o);
  if (half == 0) out[(size_t)d * 32 + j] = e / sum;
}

// =================================================================================
extern "C" void kernel_launch(void* const* d_in, const int* in_sizes, int n_in,
                              void* d_out, int out_size, void* d_ws, size_t ws_size,
                              hipStream_t stream) {
  (void)in_sizes; (void)n_in; (void)out_size; (void)ws_size;
  const float* emb   = (const float*)d_in[0];
  const float* ipw   = (const float*)d_in[1];
  const float* ipb   = (const float*)d_in[2];
  const float* opw   = (const float*)d_in[3];
  const float* opb   = (const float*)d_in[4];
  const float* w1    = (const float*)d_in[5];
  const float* root1 = (const float*)d_in[6];
  const float* b1    = (const float*)d_in[7];
  const float* w2    = (const float*)d_in[8];
  const float* root2 = (const float*)d_in[9];
  const float* b2    = (const float*)d_in[10];
  const int*   eidx  = (const int*)d_in[11];
  const int*   etype = (const int*)d_in[12];
  const int* srcp = eidx;
  const int* dstp = eidx + NEDGE;

  unsigned char* ws = (unsigned char*)d_ws;
  size_t off_b = 0;
  auto alloc = [&](size_t bytes) {
    unsigned char* p = ws + off_b;
    off_b += (bytes + 255) & ~(size_t)255;
    return p;
  };

  // Region R reused sequentially: qkv 153.6MB -> Y1 108.8MB -> Y2 54.4MB
  unsigned char* R = alloc(153600000);
  __hip_bfloat16* qkv = (__hip_bfloat16*)R;
  __hip_bfloat16* Y1  = (__hip_bfloat16*)R;
  __hip_bfloat16* Y2  = (__hip_bfloat16*)R;
  __hip_bfloat16* o0  = (__hip_bfloat16*)alloc(12800000);
  __hip_bfloat16* x1b = (__hip_bfloat16*)alloc(6400000);
  int*            cnt = (int*)alloc(3200000);
  int*            offs = (int*)alloc((NNODES + 1) * 4);
  int*            fill = (int*)alloc(NNODES * 4);
  int*            part = (int*)alloc(SCAN_NB * 4);
  unsigned*       sorted = (unsigned*)alloc(NEDGE * 4);
  float*          scales = (float*)alloc(NEDGE * 4);
  __hip_bfloat16* BTqkv  = (__hip_bfloat16*)alloc(98304);
  __hip_bfloat16* BToutT = (__hip_bfloat16*)alloc(32768);
  __hip_bfloat16* BT1    = (__hip_bfloat16*)alloc(278528);
  __hip_bfloat16* BT2    = (__hip_bfloat16*)alloc(69632);
  __hip_bfloat16* BW     = (__hip_bfloat16*)alloc(278528);  // 1088 x 128
  float*          bias1  = (float*)alloc(4352);

  // 1) memsets + merged prep (weights + bias1 + edge counts)
  hipMemsetAsync(cnt, 0, (size_t)RREL * NNODES * sizeof(int), stream);
  hipMemsetAsync(fill, 0, (size_t)NNODES * sizeof(int), stream);
  mega_prep<<<dim3(3391), dim3(256), 0, stream>>>(
      ipw, opw, w1, root1, w2, root2, opb, dstp, etype,
      BTqkv, BToutT, BT1, BT2, bias1, cnt);
  scan1<<<dim3(SCAN_NB), dim3(256), 0, stream>>>(cnt, offs, part);
  scan2<<<dim3(1), dim3(256), 0, stream>>>(part);
  scan3<<<dim3(SCAN_NB), dim3(256), 0, stream>>>(offs, part);
  scatter_edges<<<dim3((NEDGE + 255) / 256), dim3(256), 0, stream>>>(
      srcp, dstp, etype, cnt, offs, fill, sorted, scales);

  // 2) BW = (Wo^T B1) fold: (1088 x 128) = BT1 @ BToutT^T
  gemm_strips<128><<<dim3(9, 1), dim3(256), 0, stream>>>(
      BT1, BToutT, nullptr, BW, 1088, 128, 128, 1);

  // 3) QKV: K/V strips (strip index fastest -> A panel L2-reuse), then Q strip
  qkv_kv<<<dim3(2, 1563), dim3(256), 0, stream>>>(emb, BTqkv, ipb, qkv);
  qkv_q<<<dim3(391), dim3(256), 0, stream>>>(emb, BTqkv, ipb, qkv);

  // 4) attention -> o0 (4 nodes/wave, int4 loads)
  attn_kernel<<<dim3(3125), dim3(256), 0, stream>>>(qkv, o0);

  // 5) Y1 = o0 @ BW (+bias1): 9 single-strip col groups (A is L2-resident)
  gemm_strips<128><<<dim3(391, 9), dim3(256), 0, stream>>>(
      o0, BW, bias1, Y1, NNODES, 1088, 1088, 1);

  // 6) fused layer1 -> x1b
  fused1<<<dim3(NNODES / 4), dim3(256), 0, stream>>>(
      offs, sorted, scales, (const ushort*)Y1, b1, x1b);

  // 7) Y2 = x1b @ [root2 | W2_r]: 5 single-strip col groups
  gemm_strips<64><<<dim3(391, 5), dim3(256), 0, stream>>>(
      x1b, BT2, nullptr, Y2, NNODES, 544, 544, 1);

  // 8) fused layer2 + softmax -> out
  fused2<<<dim3(NNODES / 4), dim3(256), 0, stream>>>(
      offs, sorted, scales, (const ushort*)Y2, b2, (float*)d_out);
}

// Round 22
// 319.828 us; speedup vs baseline: 1.0578x; 1.0578x over previous
//
#include <hip/hip_runtime.h>
#include <hip/hip_bf16.h>
#include <math.h>

#define NNODES 50000
#define NEDGE 625000
#define RREL 16
#define SCAN_NB 196   // ceil(50000/256)

typedef __attribute__((ext_vector_type(8))) short short8;
typedef __attribute__((ext_vector_type(4))) float f32x4;

__device__ __forceinline__ float bfu(ushort u) {
  return __uint_as_float(((unsigned)u) << 16);
}
__device__ __forceinline__ ushort f2b(float f) {
  __hip_bfloat16 h = __float2bfloat16(f);
  return *(ushort*)&h;
}

// ---------------- mega_prep: weight prep + bias1 fold-prep + edge counts ----------
// blocks [0,944): prep weights; [944,949): bias1' = bo @ B1; [949,3391): count edges
__global__ __launch_bounds__(256) void mega_prep(
    const float* __restrict__ ipw, const float* __restrict__ opw,
    const float* __restrict__ w1, const float* __restrict__ root1,
    const float* __restrict__ w2, const float* __restrict__ root2,
    const float* __restrict__ opb,
    const int* __restrict__ dst, const int* __restrict__ et,
    __hip_bfloat16* __restrict__ BTqkv, __hip_bfloat16* __restrict__ BToutT,
    __hip_bfloat16* __restrict__ BT1, __hip_bfloat16* __restrict__ BT2,
    float* __restrict__ bias1, int* __restrict__ cnt) {
  int b = blockIdx.x, t = threadIdx.x;
  if (b < 944) {
    int i = b * 256 + t;
    if (i < 49152) {
      BTqkv[i] = __float2bfloat16(ipw[i]);
    } else if (i < 65536) {
      int j = i - 49152; int m = j / 128, c = j % 128;
      BToutT[j] = __float2bfloat16(opw[c * 128 + m]);
    } else if (i < 65536 + 139264) {
      int j = i - 65536; int c = j / 128, k = j % 128;
      float v;
      if (c < 64) v = root1[k * 64 + c];
      else { int r = (c - 64) >> 6, o = (c - 64) & 63; v = w1[r * 8192 + k * 64 + o]; }
      BT1[j] = __float2bfloat16(v);
    } else if (i < 65536 + 139264 + 34816) {
      int j = i - 65536 - 139264; int c = j / 64, k = j % 64;
      float v;
      if (c < 32) v = root2[k * 32 + c];
      else { int r = (c - 32) >> 5, o = (c - 32) & 31; v = w2[r * 2048 + k * 32 + o]; }
      BT2[j] = __float2bfloat16(v);
    }
  } else if (b < 949) {
    int j = (b - 944) * 256 + t;
    if (j < 1088) {
      float s = 0.f;
      if (j < 64) {
        for (int c = 0; c < 128; c++) s += opb[c] * root1[c * 64 + j];
      } else {
        int r = (j - 64) >> 6, o = (j - 64) & 63;
        for (int c = 0; c < 128; c++) s += opb[c] * w1[r * 8192 + c * 64 + o];
      }
      bias1[j] = s;
    }
  } else {
    int e = (b - 949) * 256 + t;
    if (e < NEDGE) atomicAdd(&cnt[et[e] * NNODES + dst[e]], 1);
  }
}

// ---------------- QKV GEMM: strip-loop, batched A staging + hoisted B loads -------
__global__ __launch_bounds__(256) void qkv_gemm(
    const float* __restrict__ A, const __hip_bfloat16* __restrict__ BT,
    const float* __restrict__ bias, __hip_bfloat16* __restrict__ C) {
  __shared__ ushort As[128 * 128];   // 32KB
  __shared__ ushort Cs[128 * 136];   // 34.8KB
  const int t = threadIdx.x;
  const long row0 = (long)blockIdx.x * 128;

  // batched staging: issue ALL 16 loads, then cvt+LDS
  {
    float4 fa[16];
#pragma unroll
    for (int it = 0; it < 8; it++) {
      int c = t + it * 256;
      int r = c >> 4, cc = c & 15;
      long gm = row0 + r; if (gm > 199999) gm = 199999;
      const float* ap = A + gm * 128 + cc * 8;
      fa[2 * it]     = *(const float4*)ap;
      fa[2 * it + 1] = *(const float4*)(ap + 4);
    }
#pragma unroll
    for (int it = 0; it < 8; it++) {
      int c = t + it * 256;
      int r = c >> 4, cc = c & 15;
      int4 v = make_int4(0, 0, 0, 0);
      if (row0 + r < 200000) {
        float4 f0 = fa[2 * it], f1 = fa[2 * it + 1];
        v.x = (int)f2b(f0.x) | ((int)f2b(f0.y) << 16);
        v.y = (int)f2b(f0.z) | ((int)f2b(f0.w) << 16);
        v.z = (int)f2b(f1.x) | ((int)f2b(f1.y) << 16);
        v.w = (int)f2b(f1.z) | ((int)f2b(f1.w) << 16);
      }
      *(int4*)(As + r * 128 + ((cc ^ (r & 7)) * 8)) = v;
    }
  }
  __syncthreads();

  const int lane = t & 63, w = t >> 6;
  const int wr = (w >> 1) * 64, wc = (w & 1) * 64;
  const int lrow = lane & 15, lk = lane >> 4;
  const int nstrips = (row0 < NNODES) ? 3 : 2;

  for (int s = 0; s < nstrips; s++) {
    const int col0 = (s == 2) ? 0 : 128 + s * 128;
    const long Meff = (s == 2) ? NNODES : 200000;

    const ushort* bp[4];
#pragma unroll
    for (int j = 0; j < 4; j++)
      bp[j] = (const ushort*)BT + (long)(col0 + wc + j * 16 + lrow) * 128 + lk * 8;

    short8 bfr[4][4];
#pragma unroll
    for (int k0 = 0; k0 < 4; k0++)
#pragma unroll
      for (int j = 0; j < 4; j++)
        bfr[k0][j] = *(const short8*)(bp[j] + k0 * 32);

    f32x4 acc[4][4];
#pragma unroll
    for (int i = 0; i < 4; i++)
#pragma unroll
      for (int j = 0; j < 4; j++) acc[i][j] = (f32x4){0.f, 0.f, 0.f, 0.f};

#pragma unroll
    for (int k0 = 0; k0 < 4; k0++) {
      const int cb = k0 * 4 + lk;
      short8 af[4];
#pragma unroll
      for (int i = 0; i < 4; i++) {
        int ra = wr + i * 16 + lrow;
        af[i] = *(const short8*)(As + ra * 128 + ((cb ^ (ra & 7)) * 8));
      }
#pragma unroll
      for (int i = 0; i < 4; i++)
#pragma unroll
        for (int j = 0; j < 4; j++)
          acc[i][j] = __builtin_amdgcn_mfma_f32_16x16x32_bf16(af[i], bfr[k0][j], acc[i][j], 0, 0, 0);
    }

    __syncthreads();
#pragma unroll
    for (int j = 0; j < 4; j++) {
      int coll = wc + j * 16 + lrow;
      float bv = bias[col0 + coll];
#pragma unroll
      for (int i = 0; i < 4; i++) {
        int rbase = wr + i * 16 + lk * 4;
#pragma unroll
        for (int q = 0; q < 4; q++)
          Cs[(rbase + q) * 136 + coll] = f2b(acc[i][j][q] + bv);
      }
    }
    __syncthreads();
#pragma unroll
    for (int idx = t; idx < 128 * 16; idx += 256) {
      int r = idx >> 4, k = idx & 15;
      long gm = row0 + r;
      if (gm < Meff)
        *(int4*)((ushort*)C + gm * 384 + col0 + k * 8) = *(const int4*)(Cs + r * 136 + k * 8);
    }
  }
}

// ---------------- generic strip-loop bf16 GEMM (batched A + hoisted B) ------------
#define EPILOGUE_STORE(MEFF, NCOLS, LDC, BIASEXPR)                              \
  for (int p = 0; p < 2; p++) {                                                 \
    __syncthreads();                                                            \
    if ((w >> 1) == p) {                                                        \
      _Pragma("unroll")                                                         \
      for (int j = 0; j < 4; j++) {                                             \
        int coll = wc + j * 16 + lrow;                                          \
        float bv = (BIASEXPR);                                                  \
        _Pragma("unroll")                                                       \
        for (int i = 0; i < 4; i++) {                                           \
          int rloc = i * 16 + lk * 4;                                           \
          _Pragma("unroll")                                                     \
          for (int q = 0; q < 4; q++)                                           \
            Cs[(rloc + q) * 132 + coll] = f2b(acc[i][j][q] + bv);               \
        }                                                                       \
      }                                                                         \
    }                                                                           \
    __syncthreads();                                                            \
    _Pragma("unroll")                                                           \
    for (int idx = t; idx < 64 * 16; idx += 256) {                              \
      int r = idx >> 4, k = idx & 15;                                           \
      long gm = row0 + p * 64 + r;                                              \
      int col = col0 + k * 8;                                                   \
      if (gm < (MEFF) && col < (NCOLS))                                         \
        *(int4*)((ushort*)C + gm * (LDC) + col) = *(const int4*)(Cs + r * 132 + k * 8); \
    }                                                                           \
  }

template <int K>
__global__ __launch_bounds__(256) void gemm_strips(
    const __hip_bfloat16* __restrict__ Av, const __hip_bfloat16* __restrict__ BT,
    const float* __restrict__ bias, __hip_bfloat16* __restrict__ C,
    int M, int N, int ldc, int spg) {
  constexpr int CPR = K / 8;
  constexpr int NIT = 128 * CPR / 256;
  constexpr int NK0 = K / 32;
  __shared__ ushort As[128 * K];
  __shared__ ushort Cs[64 * 132];
  const int t = threadIdx.x;
  const long row0 = (long)blockIdx.x * 128;

  {
    int4 st[NIT];
#pragma unroll
    for (int it = 0; it < NIT; it++) {
      int c = t + it * 256;
      int r = c / CPR, cc = c % CPR;
      long gm = row0 + r; if (gm > M - 1) gm = M - 1;
      st[it] = *(const int4*)((const ushort*)Av + gm * K + cc * 8);
    }
#pragma unroll
    for (int it = 0; it < NIT; it++) {
      int c = t + it * 256;
      int r = c / CPR, cc = c % CPR;
      int4 v = (row0 + r < M) ? st[it] : make_int4(0, 0, 0, 0);
      *(int4*)(As + r * K + ((cc ^ (r & 7)) * 8)) = v;
    }
  }
  __syncthreads();

  const int lane = t & 63, w = t >> 6;
  const int wr = (w >> 1) * 64, wc = (w & 1) * 64;
  const int lrow = lane & 15, lk = lane >> 4;
  const int nstrips = (N + 127) / 128;
  const int sbeg = blockIdx.y * spg;
  const int send = min(sbeg + spg, nstrips);

  for (int s = sbeg; s < send; s++) {
    const int col0 = s * 128;

    const ushort* bp[4];
#pragma unroll
    for (int j = 0; j < 4; j++) {
      int gn = col0 + wc + j * 16 + lrow;
      if (gn > N - 1) gn = N - 1;
      bp[j] = (const ushort*)BT + (long)gn * K + lk * 8;
    }

    short8 bfr[NK0][4];
#pragma unroll
    for (int k0 = 0; k0 < NK0; k0++)
#pragma unroll
      for (int j = 0; j < 4; j++)
        bfr[k0][j] = *(const short8*)(bp[j] + k0 * 32);

    f32x4 acc[4][4];
#pragma unroll
    for (int i = 0; i < 4; i++)
#pragma unroll
      for (int j = 0; j < 4; j++) acc[i][j] = (f32x4){0.f, 0.f, 0.f, 0.f};

#pragma unroll
    for (int k0 = 0; k0 < NK0; k0++) {
      const int cb = k0 * 4 + lk;
      short8 af[4];
#pragma unroll
      for (int i = 0; i < 4; i++) {
        int ra = wr + i * 16 + lrow;
        af[i] = *(const short8*)(As + ra * K + ((cb ^ (ra & 7)) * 8));
      }
#pragma unroll
      for (int i = 0; i < 4; i++)
#pragma unroll
        for (int j = 0; j < 4; j++)
          acc[i][j] = __builtin_amdgcn_mfma_f32_16x16x32_bf16(af[i], bfr[k0][j], acc[i][j], 0, 0, 0);
    }

    EPILOGUE_STORE(M, N, ldc, bias ? bias[min(col0 + coll, N - 1)] : 0.f)
  }
}

// ---------------- attention: 4 nodes/wave, int4 loads -----------------------------
__global__ __launch_bounds__(256) void attn_kernel(
    const __hip_bfloat16* __restrict__ qkv, __hip_bfloat16* __restrict__ o0) {
  int w = threadIdx.x >> 6, lane = threadIdx.x & 63;
  int nl = lane >> 4, cl = lane & 15;
  long n = (long)blockIdx.x * 16 + w * 4 + nl;
  const ushort* base = (const ushort*)qkv;
  int4 qv = *(const int4*)(base + n * 384 + cl * 8);
  int4 kq[4], vq[4];
#pragma unroll
  for (int m = 0; m < 4; m++) {
    const ushort* p = base + ((long)m * NNODES + n) * 384;
    kq[m] = *(const int4*)(p + 128 + cl * 8);
    vq[m] = *(const int4*)(p + 256 + cl * 8);
  }
  float qf[8];
  {
    const uint* qu = (const uint*)&qv;
#pragma unroll
    for (int x = 0; x < 4; x++) {
      qf[2 * x] = bfu(qu[x] & 0xffff);
      qf[2 * x + 1] = bfu(qu[x] >> 16);
    }
  }
  float s[4];
#pragma unroll
  for (int m = 0; m < 4; m++) {
    const uint* ku = (const uint*)&kq[m];
    float p = 0.f;
#pragma unroll
    for (int x = 0; x < 4; x++)
      p += qf[2 * x] * bfu(ku[x] & 0xffff) + qf[2 * x + 1] * bfu(ku[x] >> 16);
    p += __shfl_xor(p, 1);
    p += __shfl_xor(p, 2);
    s[m] = p * 0.17677669529663687f;  // 1/sqrt(32)
  }
  float mx = fmaxf(fmaxf(s[0], s[1]), fmaxf(s[2], s[3]));
  float e[4], sum = 0.f;
#pragma unroll
  for (int m = 0; m < 4; m++) { e[m] = __expf(s[m] - mx); sum += e[m]; }
  float inv = 1.0f / sum;
  float o[8] = {0.f, 0.f, 0.f, 0.f, 0.f, 0.f, 0.f, 0.f};
#pragma unroll
  for (int m = 0; m < 4; m++) {
    const uint* vu = (const uint*)&vq[m];
    float wgt = e[m] * inv;
#pragma unroll
    for (int x = 0; x < 4; x++) {
      o[2 * x]     += wgt * bfu(vu[x] & 0xffff);
      o[2 * x + 1] += wgt * bfu(vu[x] >> 16);
    }
  }
  int4 ov;
  uint* ou = (uint*)&ov;
#pragma unroll
  for (int x = 0; x < 4; x++)
    ou[x] = (uint)f2b(o[2 * x]) | ((uint)f2b(o[2 * x + 1]) << 16);
  *(int4*)((ushort*)o0 + n * 128 + cl * 8) = ov;
}

// ---------------- CSR build ------------------------------------------------------
__global__ __launch_bounds__(256) void scan1(
    const int* __restrict__ cnt, int* __restrict__ off, int* __restrict__ part) {
  int t = threadIdx.x, b = blockIdx.x;
  int i = b * 256 + t;
  int v = 0;
  if (i < NNODES) {
#pragma unroll
    for (int r = 0; r < RREL; r++) v += cnt[r * NNODES + i];
  }
  __shared__ int sm[256];
  sm[t] = v;
  __syncthreads();
#pragma unroll
  for (int o = 1; o < 256; o <<= 1) {
    int x = (t >= o) ? sm[t - o] : 0;
    __syncthreads();
    sm[t] += x;
    __syncthreads();
  }
  if (i < NNODES) off[i] = sm[t] - v;
  if (t == 255) part[b] = sm[t];
}

__global__ __launch_bounds__(256) void scan2(int* __restrict__ part) {
  int t = threadIdx.x;
  int v = (t < SCAN_NB) ? part[t] : 0;
  __shared__ int sm[256];
  sm[t] = v;
  __syncthreads();
#pragma unroll
  for (int o = 1; o < 256; o <<= 1) {
    int x = (t >= o) ? sm[t - o] : 0;
    __syncthreads();
    sm[t] += x;
    __syncthreads();
  }
  if (t < SCAN_NB) part[t] = sm[t] - v;
}

__global__ __launch_bounds__(256) void scan3(int* __restrict__ off, const int* __restrict__ part) {
  int i = blockIdx.x * 256 + threadIdx.x;
  if (i < NNODES) off[i] += part[blockIdx.x];
  if (i == 0) off[NNODES] = NEDGE;
}

__global__ __launch_bounds__(256) void scatter_edges(
    const int* __restrict__ src, const int* __restrict__ dst, const int* __restrict__ et,
    const int* __restrict__ cnt, const int* __restrict__ off,
    int* __restrict__ fill, unsigned* __restrict__ sorted, float* __restrict__ scales) {
  int e = blockIdx.x * 256 + threadIdx.x;
  if (e >= NEDGE) return;
  int d = dst[e], r = et[e], s = src[e];
  int pos = off[d] + atomicAdd(&fill[d], 1);
  sorted[pos] = (unsigned)s | ((unsigned)r << 16);
  scales[pos] = 1.0f / (float)cnt[r * NNODES + d];
}

// ---------------- fused layer1: 8-deep gather pipeline + relu ---------------------
__global__ __launch_bounds__(256) void fused1(
    const int* __restrict__ off, const unsigned* __restrict__ sorted,
    const float* __restrict__ scales, const ushort* __restrict__ Y1,
    const float* __restrict__ b1, __hip_bfloat16* __restrict__ x1b) {
  int w = threadIdx.x >> 6, lane = threadIdx.x & 63;
  int d = blockIdx.x * 4 + w;
  int s0 = off[d], s1 = off[d + 1];
  float a[8];
  a[0] = bfu(Y1[(size_t)d * 1088 + lane]) + b1[lane];
#pragma unroll
  for (int j = 1; j < 8; j++) a[j] = 0.f;
  int i = s0;
  for (; i + 7 < s1; i += 8) {
    unsigned p[8];
    float c[8];
#pragma unroll
    for (int j = 0; j < 8; j++) { p[j] = sorted[i + j]; c[j] = scales[i + j]; }
#pragma unroll
    for (int j = 0; j < 8; j++)
      a[j] += bfu(Y1[(size_t)(p[j] & 0xFFFF) * 1088 + 64 + (p[j] >> 16) * 64 + lane]) * c[j];
  }
  for (; i < s1; i++) {
    unsigned p = sorted[i];
    a[0] += bfu(Y1[(size_t)(p & 0xFFFF) * 1088 + 64 + (p >> 16) * 64 + lane]) * scales[i];
  }
  float acc = ((a[0] + a[1]) + (a[2] + a[3])) + ((a[4] + a[5]) + (a[6] + a[7]));
  x1b[(size_t)d * 64 + lane] = __float2bfloat16(fmaxf(acc, 0.f));
}

// ---------------- fused layer2: 4-way (2 lanes x 2 accs) + softmax -> out ---------
__global__ __launch_bounds__(256) void fused2(
    const int* __restrict__ off, const unsigned* __restrict__ sorted,
    const float* __restrict__ scales, const ushort* __restrict__ Y2,
    const float* __restrict__ b2, float* __restrict__ out) {
  int w = threadIdx.x >> 6, lane = threadIdx.x & 63;
  int d = blockIdx.x * 4 + w;
  int j = lane & 31, half = lane >> 5;
  int s0 = off[d], s1 = off[d + 1];
  float a0 = 0.f, a1 = 0.f, a2 = 0.f, a3 = 0.f;
  int i = s0 + half;
  for (; i + 6 < s1; i += 8) {
    unsigned p0 = sorted[i], p1 = sorted[i + 2], p2 = sorted[i + 4], p3 = sorted[i + 6];
    float c0 = scales[i], c1 = scales[i + 2], c2 = scales[i + 4], c3 = scales[i + 6];
    a0 += bfu(Y2[(size_t)(p0 & 0xFFFF) * 544 + 32 + (p0 >> 16) * 32 + j]) * c0;
    a1 += bfu(Y2[(size_t)(p1 & 0xFFFF) * 544 + 32 + (p1 >> 16) * 32 + j]) * c1;
    a2 += bfu(Y2[(size_t)(p2 & 0xFFFF) * 544 + 32 + (p2 >> 16) * 32 + j]) * c2;
    a3 += bfu(Y2[(size_t)(p3 & 0xFFFF) * 544 + 32 + (p3 >> 16) * 32 + j]) * c3;
  }
  for (; i < s1; i += 2) {
    unsigned p = sorted[i];
    a0 += bfu(Y2[(size_t)(p & 0xFFFF) * 544 + 32 + (p >> 16) * 32 + j]) * scales[i];
  }
  float acc = (a0 + a1) + (a2 + a3);
  acc += __shfl_xor(acc, 32);
  float v = acc + bfu(Y2[(size_t)d * 544 + j]) + b2[j];
  float mx = v;
#pragma unroll
  for (int o = 16; o; o >>= 1) mx = fmaxf(mx, __shfl_xor(mx, o));
  float e = __expf(v - mx);
  float sum = e;
#pragma unroll
  for (int o = 16; o; o >>= 1) sum += __shfl_xor(sum, o);
  if (half == 0) out[(size_t)d * 32 + j] = e / sum;
}

// =================================================================================
extern "C" void kernel_launch(void* const* d_in, const int* in_sizes, int n_in,
                              void* d_out, int out_size, void* d_ws, size_t ws_size,
                              hipStream_t stream) {
  (void)in_sizes; (void)n_in; (void)out_size; (void)ws_size;
  const float* emb   = (const float*)d_in[0];
  const float* ipw   = (const float*)d_in[1];
  const float* ipb   = (const float*)d_in[2];
  const float* opw   = (const float*)d_in[3];
  const float* opb   = (const float*)d_in[4];
  const float* w1    = (const float*)d_in[5];
  const float* root1 = (const float*)d_in[6];
  const float* b1    = (const float*)d_in[7];
  const float* w2    = (const float*)d_in[8];
  const float* root2 = (const float*)d_in[9];
  const float* b2    = (const float*)d_in[10];
  const int*   eidx  = (const int*)d_in[11];
  const int*   etype = (const int*)d_in[12];
  const int* srcp = eidx;
  const int* dstp = eidx + NEDGE;

  unsigned char* ws = (unsigned char*)d_ws;
  size_t off_b = 0;
  auto alloc = [&](size_t bytes) {
    unsigned char* p = ws + off_b;
    off_b += (bytes + 255) & ~(size_t)255;
    return p;
  };

  // Region R reused sequentially: qkv 153.6MB -> Y1 108.8MB -> Y2 54.4MB
  unsigned char* R = alloc(153600000);
  __hip_bfloat16* qkv = (__hip_bfloat16*)R;
  __hip_bfloat16* Y1  = (__hip_bfloat16*)R;
  __hip_bfloat16* Y2  = (__hip_bfloat16*)R;
  __hip_bfloat16* o0  = (__hip_bfloat16*)alloc(12800000);
  __hip_bfloat16* x1b = (__hip_bfloat16*)alloc(6400000);
  int*            cnt = (int*)alloc(3200000);
  int*            offs = (int*)alloc((NNODES + 1) * 4);
  int*            fill = (int*)alloc(NNODES * 4);
  int*            part = (int*)alloc(SCAN_NB * 4);
  unsigned*       sorted = (unsigned*)alloc(NEDGE * 4);
  float*          scales = (float*)alloc(NEDGE * 4);
  __hip_bfloat16* BTqkv  = (__hip_bfloat16*)alloc(98304);
  __hip_bfloat16* BToutT = (__hip_bfloat16*)alloc(32768);
  __hip_bfloat16* BT1    = (__hip_bfloat16*)alloc(278528);
  __hip_bfloat16* BT2    = (__hip_bfloat16*)alloc(69632);
  __hip_bfloat16* BW     = (__hip_bfloat16*)alloc(278528);  // 1088 x 128
  float*          bias1  = (float*)alloc(4352);

  // 1) memsets + merged prep (weights + bias1 + edge counts)
  hipMemsetAsync(cnt, 0, (size_t)RREL * NNODES * sizeof(int), stream);
  hipMemsetAsync(fill, 0, (size_t)NNODES * sizeof(int), stream);
  mega_prep<<<dim3(3391), dim3(256), 0, stream>>>(
      ipw, opw, w1, root1, w2, root2, opb, dstp, etype,
      BTqkv, BToutT, BT1, BT2, bias1, cnt);
  scan1<<<dim3(SCAN_NB), dim3(256), 0, stream>>>(cnt, offs, part);
  scan2<<<dim3(1), dim3(256), 0, stream>>>(part);
  scan3<<<dim3(SCAN_NB), dim3(256), 0, stream>>>(offs, part);
  scatter_edges<<<dim3((NEDGE + 255) / 256), dim3(256), 0, stream>>>(
      srcp, dstp, etype, cnt, offs, fill, sorted, scales);

  // 2) BW = (Wo^T B1) fold: (1088 x 128) = BT1 @ BToutT^T
  gemm_strips<128><<<dim3(9, 1), dim3(256), 0, stream>>>(
      BT1, BToutT, nullptr, BW, 1088, 128, 128, 1);

  // 3) QKV (strip-loop, batched staging): (200000 x 128 f32) @ (128 x 384) -> qkv
  qkv_gemm<<<dim3(1563), dim3(256), 0, stream>>>(emb, BTqkv, ipb, qkv);

  // 4) attention -> o0 (4 nodes/wave, int4 loads)
  attn_kernel<<<dim3(3125), dim3(256), 0, stream>>>(qkv, o0);

  // 5) Y1 = o0 @ BW (+bias1): (50000 x 128) @ (128 x 1088), 9 strips in 3 groups
  gemm_strips<128><<<dim3(391, 3), dim3(256), 0, stream>>>(
      o0, BW, bias1, Y1, NNODES, 1088, 1088, 3);

  // 6) fused layer1 -> x1b
  fused1<<<dim3(NNODES / 4), dim3(256), 0, stream>>>(
      offs, sorted, scales, (const ushort*)Y1, b1, x1b);

  // 7) Y2 = x1b @ [root2 | W2_r]: (50000 x 64) @ (64 x 544), 5 strips in 2 groups
  gemm_strips<64><<<dim3(391, 2), dim3(256), 0, stream>>>(
      x1b, BT2, nullptr, Y2, NNODES, 544, 544, 3);

  // 8) fused layer2 + softmax -> out
  fused2<<<dim3(NNODES / 4), dim3(256), 0, stream>>>(
      offs, sorted, scales, (const ushort*)Y2, b2, (float*)d_out);
}